// Round 1
// baseline (14141.068 us; speedup 1.0000x reference)
//
#include <hip/hip_runtime.h>
#include <math.h>

// GRU layer: B=64, T=512, I=512, H=1024, fp32.
// One kernel launch per timestep; h-history stored in d_out itself:
//   out[b][t][:] == h_t, step t reads out[..,t-1,..] (t==0 -> h=0).
// Each block owns JB=4 hidden indices j (all 3 gates, all 64 batch rows).
// Grid = H/JB = 256 blocks (one per CU). K-loop over 1536 (512 x-part via
// W_i_*, 1024 h-part via W_h_*) in chunks of 128 staged in LDS.

#define BB 64
#define TT 512
#define II 512
#define HH 1024
#define JB 4
#define CK 128
#define PAD 132   // 132*4B = 528B row stride: 16B-aligned, balanced LDS banks

__device__ __forceinline__ void fma4(float4& a, const float4 xv, const float4 w) {
    a.x += xv.x * w.x;
    a.y += xv.y * w.y;
    a.z += xv.z * w.z;
    a.w += xv.w * w.w;
}

__device__ __forceinline__ void accum_chunk(
    const float* __restrict__ xsrow,
    const float* __restrict__ wr, const float* __restrict__ wz,
    const float* __restrict__ wn,
    float4& aR, float4& aZ, float4& aN)
{
#pragma unroll
    for (int k4 = 0; k4 < CK / 4; ++k4) {
        float4 xv = *(const float4*)(xsrow + k4 * 4);
        fma4(aR, xv, *(const float4*)(wr + k4 * 4));
        fma4(aZ, xv, *(const float4*)(wz + k4 * 4));
        fma4(aN, xv, *(const float4*)(wn + k4 * 4));
    }
}

__global__ __launch_bounds__(256) void gru_step(
    const float* __restrict__ x,
    const float* __restrict__ Wir, const float* __restrict__ Whr,
    const float* __restrict__ Wiz, const float* __restrict__ Whz,
    const float* __restrict__ Win, const float* __restrict__ Whn,
    const float* __restrict__ bir, const float* __restrict__ bhr,
    const float* __restrict__ biz, const float* __restrict__ bhz,
    const float* __restrict__ bin_, const float* __restrict__ bhn,
    float* __restrict__ out, int t)
{
    __shared__ float xs[BB][PAD];
    const int tid = threadIdx.x;
    const int b   = tid & 63;
    const int jg  = tid >> 6;                      // 0..3, wave-uniform
    const int j   = __builtin_amdgcn_readfirstlane((int)blockIdx.x * JB + jg);

    float4 aR  = {0.f, 0.f, 0.f, 0.f};
    float4 aZ  = {0.f, 0.f, 0.f, 0.f};
    float4 aXN = {0.f, 0.f, 0.f, 0.f};
    float4 aHN = {0.f, 0.f, 0.f, 0.f};

    // ---------- x part: K = 512, weights W_i_* ----------
    const float* xbase = x + (size_t)t * II;
    for (int kc = 0; kc < II / CK; ++kc) {
        // stage 64 x 128 tile: 2048 float4 loads by 256 threads
#pragma unroll
        for (int i = 0; i < 8; ++i) {
            int f   = tid + 256 * i;
            int row = f >> 5;           // 32 float4 per row
            int c4  = f & 31;
            *(float4*)&xs[row][c4 * 4] =
                *(const float4*)(xbase + (size_t)row * (TT * II) + kc * CK + c4 * 4);
        }
        __syncthreads();
        accum_chunk(&xs[b][0],
                    Wir + (size_t)j * II + kc * CK,
                    Wiz + (size_t)j * II + kc * CK,
                    Win + (size_t)j * II + kc * CK,
                    aR, aZ, aXN);
        __syncthreads();
    }

    // ---------- h part: K = 1024, weights W_h_* (skip at t==0, h=0) ----------
    if (t > 0) {
        const float* hbase = out + (size_t)(t - 1) * HH;
        for (int kc = 0; kc < HH / CK; ++kc) {
#pragma unroll
            for (int i = 0; i < 8; ++i) {
                int f   = tid + 256 * i;
                int row = f >> 5;
                int c4  = f & 31;
                *(float4*)&xs[row][c4 * 4] =
                    *(const float4*)(hbase + (size_t)row * (TT * HH) + kc * CK + c4 * 4);
            }
            __syncthreads();
            accum_chunk(&xs[b][0],
                        Whr + (size_t)j * HH + kc * CK,
                        Whz + (size_t)j * HH + kc * CK,
                        Whn + (size_t)j * HH + kc * CK,
                        aR, aZ, aHN);
            __syncthreads();
        }
    }

    // ---------- epilogue: gates + state update ----------
    float rpre = (aR.x + aR.y + aR.z + aR.w) + bir[j] + bhr[j];
    float zpre = (aZ.x + aZ.y + aZ.z + aZ.w) + biz[j] + bhz[j];
    float hn   = (aHN.x + aHN.y + aHN.z + aHN.w) + bhn[j];  // h@Whn + b_h_n (bias even at t=0)
    float xn   = (aXN.x + aXN.y + aXN.z + aXN.w) + bin_[j];

    float r = 1.f / (1.f + __expf(-rpre));
    float z = 1.f / (1.f + __expf(-zpre));
    float n = tanhf(xn + r * hn);

    float hprev = (t > 0) ? out[(size_t)b * (TT * HH) + (size_t)(t - 1) * HH + j] : 0.f;
    float hnew  = (1.f - z) * n + z * hprev;
    out[(size_t)b * (TT * HH) + (size_t)t * HH + j] = hnew;
}

extern "C" void kernel_launch(void* const* d_in, const int* in_sizes, int n_in,
                              void* d_out, int out_size, void* d_ws, size_t ws_size,
                              hipStream_t stream) {
    (void)in_sizes; (void)n_in; (void)d_ws; (void)ws_size; (void)out_size;

    const float* x    = (const float*)d_in[0];
    const float* Wir  = (const float*)d_in[1];
    const float* bir  = (const float*)d_in[2];
    const float* Whr  = (const float*)d_in[3];
    const float* bhr  = (const float*)d_in[4];
    const float* Wiz  = (const float*)d_in[5];
    const float* biz  = (const float*)d_in[6];
    const float* Whz  = (const float*)d_in[7];
    const float* bhz  = (const float*)d_in[8];
    const float* Win  = (const float*)d_in[9];
    const float* bin_ = (const float*)d_in[10];
    const float* Whn  = (const float*)d_in[11];
    const float* bhn  = (const float*)d_in[12];
    float* out = (float*)d_out;

    for (int t = 0; t < TT; ++t) {
        gru_step<<<dim3(HH / JB), dim3(256), 0, stream>>>(
            x, Wir, Whr, Wiz, Whz, Win, Whn,
            bir, bhr, biz, bhz, bin_, bhn, out, t);
    }
}